// Round 3
// baseline (2244.535 us; speedup 1.0000x reference)
//
#include <hip/hip_runtime.h>
#include <hip/hip_bf16.h>

#define EMB 32
#define HID 64
#define NREL 3
#define M1 8   // nodes per wave in the node-GEMM kernels

// ---- h1 storage adapters (fp32 or bf16 path, chosen by ws_size budget) ----
__device__ inline void h_store(float* p, float v) { *p = v; }
__device__ inline void h_store(__hip_bfloat16* p, float v) { *p = __float2bfloat16(v); }
__device__ inline float h_load(const float* p) { return *p; }
__device__ inline float h_load(const __hip_bfloat16* p) { return __bfloat162float(*p); }

// ---- layer-1 edge aggregation: on-the-fly embedding, chunked dst range [a,b) ----
__global__ __launch_bounds__(256) void l1edge_k(
    const int* __restrict__ src, const int* __restrict__ dst, const int* __restrict__ et,
    const int* __restrict__ sid, const int* __restrict__ cid, const int* __restrict__ pid,
    const float* __restrict__ se, const float* __restrict__ ce, const float* __restrict__ pe,
    float* __restrict__ agg, float* __restrict__ cnt, int E, int a, int b) {
  int t = blockIdx.x * 256 + threadIdx.x;
  int e = t >> 5;
  if (e >= E) return;
  int d = dst[e];
  if (d < a || d >= b) return;
  int l = t & 31;
  int s = src[e], r = et[e];
  // embedding tables: 21 KB total -> cache-resident
  float v = se[sid[s] * EMB + l] + ce[cid[s] * EMB + l] + pe[pid[s] * EMB + l];
  atomicAdd(&agg[(size_t)(d - a) * (NREL * EMB) + r * EMB + l], v);
  if (l == 0) atomicAdd(&cnt[d * NREL + r], 1.0f);
}

// ---- layer-2 edge aggregation: gather h1[src], chunked dst range [a,b) ----
template <typename HT>
__global__ __launch_bounds__(256) void l2edge_k(
    const int* __restrict__ src, const int* __restrict__ dst, const int* __restrict__ et,
    const HT* __restrict__ h1, float* __restrict__ agg, int E, int a, int b) {
  int t = blockIdx.x * 256 + threadIdx.x;
  int e = t >> 6;
  if (e >= E) return;
  int d = dst[e];
  if (d < a || d >= b) return;
  int l = t & 63;
  int s = src[e], r = et[e];
  atomicAdd(&agg[(size_t)(d - a) * (NREL * HID) + r * HID + l],
            h_load(&h1[(size_t)s * HID + l]));
}

// ---- layer-1 node GEMM for nodes [a,b): h1 = relu(b1 + x@root1 + sum_r mean_r@W1_r) ----
template <typename HT>
__global__ __launch_bounds__(256) void l1gemm_k(
    const float* __restrict__ agg, const float* __restrict__ cnt,
    const int* __restrict__ sid, const int* __restrict__ cid, const int* __restrict__ pid,
    const float* __restrict__ se, const float* __restrict__ ce, const float* __restrict__ pe,
    const float* __restrict__ root, const float* __restrict__ W, const float* __restrict__ bias,
    HT* __restrict__ h, int a, int b) {
  __shared__ float lw[(EMB + NREL * EMB) * HID];  // 128*64 fp32 = 32 KB
  for (int i = threadIdx.x; i < EMB * HID; i += 256) lw[i] = root[i];
  for (int i = threadIdx.x; i < NREL * EMB * HID; i += 256) lw[EMB * HID + i] = W[i];
  __syncthreads();
  int wave = __builtin_amdgcn_readfirstlane((blockIdx.x * 256 + threadIdx.x) >> 6);
  int lane = threadIdx.x & 63;
  int n0 = a + wave * M1;
  if (n0 >= b) return;
  int row[M1];
#pragma unroll
  for (int m = 0; m < M1; m++) row[m] = (n0 + m < b) ? (n0 + m) : (b - 1);

  float acc[M1];
  float bv = bias[lane];
#pragma unroll
  for (int m = 0; m < M1; m++) acc[m] = bv;

  {  // self (root) segment: recompute x row from embedding tables (cache-resident)
    int si[M1], ci[M1], pi[M1];
#pragma unroll
    for (int m = 0; m < M1; m++) {
      si[m] = sid[row[m]] * EMB;
      ci[m] = cid[row[m]] * EMB;
      pi[m] = pid[row[m]] * EMB;
    }
    float t[M1];
#pragma unroll
    for (int m = 0; m < M1; m++) t[m] = 0.f;
    for (int k = 0; k < EMB; k++) {
      float wv = lw[k * HID + lane];
#pragma unroll
      for (int m = 0; m < M1; m++) {
        float xv = se[si[m] + k] + ce[ci[m] + k] + pe[pi[m] + k];
        t[m] += xv * wv;
      }
    }
#pragma unroll
    for (int m = 0; m < M1; m++) acc[m] += t[m];
  }
  for (int r = 0; r < NREL; r++) {  // relation segments, scaled by 1/max(cnt,1)
    float t[M1];
#pragma unroll
    for (int m = 0; m < M1; m++) t[m] = 0.f;
    const float* wsr = &lw[(EMB + r * EMB) * HID];
    for (int k = 0; k < EMB; k++) {
      float wv = wsr[k * HID + lane];
#pragma unroll
      for (int m = 0; m < M1; m++)
        t[m] += agg[(size_t)(row[m] - a) * (NREL * EMB) + r * EMB + k] * wv;
    }
#pragma unroll
    for (int m = 0; m < M1; m++) {
      float c = fmaxf(cnt[row[m] * NREL + r], 1.0f);
      acc[m] += t[m] / c;
    }
  }
#pragma unroll
  for (int m = 0; m < M1; m++)
    if (n0 + m < b) h_store(&h[(size_t)(n0 + m) * HID + lane], fmaxf(acc[m], 0.f));
}

// ---- layer-2 node GEMM + fused pool for nodes [a,b) ----
template <typename HT>
__global__ __launch_bounds__(256) void l2gemm_pool_k(
    const HT* __restrict__ h1, const float* __restrict__ agg, const float* __restrict__ cnt,
    const float* __restrict__ root, const float* __restrict__ W, const float* __restrict__ bias,
    const float* __restrict__ linW, const int* __restrict__ batch,
    float* __restrict__ gs, float* __restrict__ gc, int a, int b) {
  __shared__ float lw[(HID + NREL * HID) * HID];  // 256*64 fp32 = 64 KB
  for (int i = threadIdx.x; i < HID * HID; i += 256) lw[i] = root[i];
  for (int i = threadIdx.x; i < NREL * HID * HID; i += 256) lw[HID * HID + i] = W[i];
  __syncthreads();
  int wave = __builtin_amdgcn_readfirstlane((blockIdx.x * 256 + threadIdx.x) >> 6);
  int lane = threadIdx.x & 63;
  int n0 = a + wave * M1;
  if (n0 >= b) return;
  int row[M1];
#pragma unroll
  for (int m = 0; m < M1; m++) row[m] = (n0 + m < b) ? (n0 + m) : (b - 1);

  float acc[M1];
  float bv = bias[lane];
#pragma unroll
  for (int m = 0; m < M1; m++) acc[m] = bv;

  {  // self (root) segment
    float t[M1];
#pragma unroll
    for (int m = 0; m < M1; m++) t[m] = 0.f;
    for (int k = 0; k < HID; k++) {
      float wv = lw[k * HID + lane];
#pragma unroll
      for (int m = 0; m < M1; m++) t[m] += h_load(&h1[(size_t)row[m] * HID + k]) * wv;
    }
#pragma unroll
    for (int m = 0; m < M1; m++) acc[m] += t[m];
  }
  for (int r = 0; r < NREL; r++) {
    float t[M1];
#pragma unroll
    for (int m = 0; m < M1; m++) t[m] = 0.f;
    const float* wsr = &lw[(HID + r * HID) * HID];
    for (int k = 0; k < HID; k++) {
      float wv = wsr[k * HID + lane];
#pragma unroll
      for (int m = 0; m < M1; m++)
        t[m] += agg[(size_t)(row[m] - a) * (NREL * HID) + r * HID + k] * wv;
    }
#pragma unroll
    for (int m = 0; m < M1; m++) {
      float c = fmaxf(cnt[row[m] * NREL + r], 1.0f);
      acc[m] += t[m] / c;
    }
  }
  // fused epilogue: relu, project 64->2, wave-reduce, atomic into per-graph sums
  float w0 = linW[lane * 2 + 0];
  float w1 = linW[lane * 2 + 1];
#pragma unroll
  for (int m = 0; m < M1; m++) {
    if (n0 + m >= b) break;
    float v = fmaxf(acc[m], 0.f);
    float t0 = v * w0;
    float t1 = v * w1;
#pragma unroll
    for (int o = 32; o > 0; o >>= 1) {
      t0 += __shfl_xor(t0, o, 64);
      t1 += __shfl_xor(t1, o, 64);
    }
    if (lane == 0) {
      int g = batch[n0 + m];
      atomicAdd(&gs[g * 2 + 0], t0);
      atomicAdd(&gs[g * 2 + 1], t1);
      atomicAdd(&gc[g], 1.0f);
    }
  }
}

__global__ __launch_bounds__(256) void final_k(
    const float* __restrict__ gs, const float* __restrict__ gc,
    const float* __restrict__ linb, float* __restrict__ out, int G) {
  int i = blockIdx.x * 256 + threadIdx.x;
  if (i >= G * 2) return;
  int g = i >> 1, o = i & 1;
  out[i] = gs[i] / fmaxf(gc[g], 1.0f) + linb[o];
}

template <typename HT>
static void run_pipeline(const int* src, const int* dst, const int* et,
                         const int* sid, const int* cid, const int* pid,
                         const float* se, const float* ce, const float* pe,
                         const float* W1, const float* root1, const float* b1,
                         const float* W2, const float* root2, const float* b2,
                         const float* linW, const float* linb, const int* batch,
                         float* cnt, float* gs, float* gc, HT* h1, float* agg,
                         int N, int E, int G, int c1, int c2, float* out,
                         hipStream_t stream) {
  hipMemsetAsync(cnt, 0, (size_t)N * 3 * sizeof(float), stream);
  hipMemsetAsync(gs, 0, (size_t)G * 3 * sizeof(float), stream);

  // phase 1: per-dst-chunk input-space aggregation + node GEMM
  for (int a = 0; a < N; a += c1) {
    int b = (a + c1 < N) ? (a + c1) : N;
    hipMemsetAsync(agg, 0, (size_t)(b - a) * (NREL * EMB) * sizeof(float), stream);
    l1edge_k<<<(unsigned)(((size_t)E * 32 + 255) / 256), 256, 0, stream>>>(
        src, dst, et, sid, cid, pid, se, ce, pe, agg, cnt, E, a, b);
    int waves = (b - a + M1 - 1) / M1;
    l1gemm_k<HT><<<(waves + 3) / 4, 256, 0, stream>>>(agg, cnt, sid, cid, pid, se, ce, pe, root1,
                                                      W1, b1, h1, a, b);
  }

  // phase 2: per-dst-chunk aggregation + node GEMM fused with pooling
  for (int a = 0; a < N; a += c2) {
    int b = (a + c2 < N) ? (a + c2) : N;
    hipMemsetAsync(agg, 0, (size_t)(b - a) * (NREL * HID) * sizeof(float), stream);
    l2edge_k<HT><<<(unsigned)(((size_t)E * 64 + 255) / 256), 256, 0, stream>>>(src, dst, et, h1,
                                                                               agg, E, a, b);
    int waves = (b - a + M1 - 1) / M1;
    l2gemm_pool_k<HT><<<(waves + 3) / 4, 256, 0, stream>>>(h1, agg, cnt, root2, W2, b2, linW,
                                                           batch, gs, gc, a, b);
  }

  final_k<<<(G * 2 + 255) / 256, 256, 0, stream>>>(gs, gc, linb, out, G);
}

extern "C" void kernel_launch(void* const* d_in, const int* in_sizes, int n_in,
                              void* d_out, int out_size, void* d_ws, size_t ws_size,
                              hipStream_t stream) {
  const int* sid = (const int*)d_in[0];
  const int* cid = (const int*)d_in[1];
  const int* pid = (const int*)d_in[2];
  const int* ei = (const int*)d_in[3];
  const int* et = (const int*)d_in[4];
  const int* batch = (const int*)d_in[5];
  const float* se = (const float*)d_in[7];
  const float* ce = (const float*)d_in[8];
  const float* pe = (const float*)d_in[9];
  const float* W1 = (const float*)d_in[10];
  const float* root1 = (const float*)d_in[11];
  const float* b1 = (const float*)d_in[12];
  const float* W2 = (const float*)d_in[13];
  const float* root2 = (const float*)d_in[14];
  const float* b2 = (const float*)d_in[15];
  const float* linW = (const float*)d_in[16];
  const float* linb = (const float*)d_in[17];
  float* out = (float*)d_out;

  const int N = in_sizes[0];
  const int E = in_sizes[4];
  const int G = out_size / 2;
  const int* src = ei;
  const int* dst = ei + E;

  // ---- strict ws budget (floats). Layout: cnt[3N] | gs[2G] | gc[G] | h1 | agg ----
  size_t capf = ws_size / sizeof(float);
  const int MINCH = 1024;  // minimum chunk (nodes) worth graph-capturing
  size_t head = (size_t)N * 3 + (size_t)G * 3;

  float* ws = (float*)d_ws;
  float* cnt = ws;
  float* gs = cnt + (size_t)N * 3;
  float* gc = gs + (size_t)G * 2;
  float* after_head = gc + (size_t)G;

  // fp32-h1 path?
  size_t fixed32 = head + (size_t)N * HID;
  size_t fixed16 = head + (size_t)N * HID / 2;  // bf16 h1 = 2 bytes/elem

  if (capf >= fixed32 + (size_t)MINCH * (NREL * HID)) {
    float* h1 = after_head;
    float* agg = h1 + (size_t)N * HID;
    size_t varf = capf - fixed32;
    size_t c1s = varf / (NREL * EMB); if (c1s > (size_t)N) c1s = N;
    size_t c2s = varf / (NREL * HID); if (c2s > (size_t)N) c2s = N;
    int c1 = (int)(c1s & ~(size_t)7); if (c1 < 8) c1 = 8;
    int c2 = (int)(c2s & ~(size_t)7); if (c2 < 8) c2 = 8;
    run_pipeline<float>(src, dst, et, sid, cid, pid, se, ce, pe, W1, root1, b1, W2, root2, b2,
                        linW, linb, batch, cnt, gs, gc, h1, agg, N, E, G, c1, c2, out, stream);
  } else if (capf >= fixed16 + (size_t)MINCH * (NREL * HID)) {
    __hip_bfloat16* h1 = (__hip_bfloat16*)after_head;
    float* agg = after_head + (size_t)N * HID / 2;
    size_t varf = capf - fixed16;
    size_t c1s = varf / (NREL * EMB); if (c1s > (size_t)N) c1s = N;
    size_t c2s = varf / (NREL * HID); if (c2s > (size_t)N) c2s = N;
    int c1 = (int)(c1s & ~(size_t)7); if (c1 < 8) c1 = 8;
    int c2 = (int)(c2s & ~(size_t)7); if (c2 < 8) c2 = 8;
    run_pipeline<__hip_bfloat16>(src, dst, et, sid, cid, pid, se, ce, pe, W1, root1, b1, W2,
                                 root2, b2, linW, linb, batch, cnt, gs, gc, h1, agg, N, E, G, c1,
                                 c2, out, stream);
  }
  // else: ws too small for any correct plan — launch nothing (fails loudly, no OOB).
}

// Round 4
// 1298.471 us; speedup vs baseline: 1.7286x; 1.7286x over previous
//
#include <hip/hip_runtime.h>
#include <hip/hip_bf16.h>

#define EMB 32
#define HID 64
#define NREL 3
#define TILE 64
#define KC 64

// ---- h1 storage adapters (fp32 or bf16 path, chosen by ws_size budget) ----
__device__ inline void h_store(float* p, float v) { *p = v; }
__device__ inline void h_store(__hip_bfloat16* p, float v) { *p = __float2bfloat16(v); }
__device__ inline float h_load(const float* p) { return *p; }
__device__ inline float h_load(const __hip_bfloat16* p) { return __bfloat162float(*p); }

// ---- layer-1 edge aggregation: on-the-fly embedding, chunked dst range [a,b) ----
__global__ __launch_bounds__(256) void l1edge_k(
    const int* __restrict__ src, const int* __restrict__ dst, const int* __restrict__ et,
    const int* __restrict__ sid, const int* __restrict__ cid, const int* __restrict__ pid,
    const float* __restrict__ se, const float* __restrict__ ce, const float* __restrict__ pe,
    float* __restrict__ agg, float* __restrict__ cnt, int E, int a, int b) {
  int t = blockIdx.x * 256 + threadIdx.x;
  int e = t >> 5;
  if (e >= E) return;
  int d = dst[e];
  if (d < a || d >= b) return;
  int l = t & 31;
  int s = src[e], r = et[e];
  float v = se[sid[s] * EMB + l] + ce[cid[s] * EMB + l] + pe[pid[s] * EMB + l];
  atomicAdd(&agg[(size_t)(d - a) * (NREL * EMB) + r * EMB + l], v);
  if (l == 0) atomicAdd(&cnt[d * NREL + r], 1.0f);
}

// ---- layer-2 edge aggregation: gather h1[src], chunked dst range [a,b) ----
template <typename HT>
__global__ __launch_bounds__(256) void l2edge_k(
    const int* __restrict__ src, const int* __restrict__ dst, const int* __restrict__ et,
    const HT* __restrict__ h1, float* __restrict__ agg, int E, int a, int b) {
  int t = blockIdx.x * 256 + threadIdx.x;
  int e = t >> 6;
  if (e >= E) return;
  int d = dst[e];
  if (d < a || d >= b) return;
  int l = t & 63;
  int s = src[e], r = et[e];
  atomicAdd(&agg[(size_t)(d - a) * (NREL * HID) + r * HID + l],
            h_load(&h1[(size_t)s * HID + l]));
}

// ---- layer-1 tiled GEMM: out h1[n] = relu(b1 + [x | agg1/cnt] @ [root1; W1]) ----
// block: 256 threads = 16x16, each 4x4; tile 64 rows x 64 cols; K = 128 in 2 chunks.
template <typename HT>
__global__ __launch_bounds__(256) void l1gemm_k(
    const float* __restrict__ agg, const float* __restrict__ cnt,
    const int* __restrict__ sid, const int* __restrict__ cid, const int* __restrict__ pid,
    const float* __restrict__ se, const float* __restrict__ ce, const float* __restrict__ pe,
    const float* __restrict__ root, const float* __restrict__ W, const float* __restrict__ bias,
    HT* __restrict__ h, int a, int b) {
  __shared__ float As[TILE][KC + 4];
  __shared__ float Ws[KC][TILE];
  const int t = threadIdx.x;
  const int tx = t & 15, ty = t >> 4;
  const int n0 = a + blockIdx.x * TILE;
  float acc[4][4] = {};

  for (int kc = 0; kc < 128 / KC; kc++) {
    __syncthreads();
#pragma unroll
    for (int p = 0; p < 4; p++) {
      int row = p * 16 + ty;          // 0..63
      int col = tx * 4;               // 0..60
      // ---- A tile ----
      int n = n0 + row;
      if (n >= b) n = b - 1;
      int k = kc * KC + col;
      float4 v;
      if (k < EMB) {  // self segment: recompute embedding (tables cache-resident)
        const float4 e1 = *(const float4*)&se[sid[n] * EMB + k];
        const float4 e2 = *(const float4*)&ce[cid[n] * EMB + k];
        const float4 e3 = *(const float4*)&pe[pid[n] * EMB + k];
        v.x = e1.x + e2.x + e3.x; v.y = e1.y + e2.y + e3.y;
        v.z = e1.z + e2.z + e3.z; v.w = e1.w + e2.w + e3.w;
      } else {
        int kk = k - EMB;
        int r = kk >> 5;
        float sc = 1.0f / fmaxf(cnt[(size_t)n * NREL + r], 1.0f);
        float4 g = *(const float4*)&agg[(size_t)(n - a) * (NREL * EMB) + kk];
        v.x = g.x * sc; v.y = g.y * sc; v.z = g.z * sc; v.w = g.w * sc;
      }
      *(float4*)&As[row][col] = v;
      // ---- W tile (k-major) ----
      int wk = kc * KC + row;  // global k for this W row
      float4 wv = (wk < EMB) ? *(const float4*)&root[wk * HID + col]
                             : *(const float4*)&W[(wk - EMB) * HID + col];
      *(float4*)&Ws[row][col] = wv;
    }
    __syncthreads();
#pragma unroll 4
    for (int kq = 0; kq < KC / 4; kq++) {
      float4 av[4], wv[4];
#pragma unroll
      for (int m = 0; m < 4; m++) av[m] = *(const float4*)&As[ty * 4 + m][kq * 4];
#pragma unroll
      for (int i = 0; i < 4; i++) wv[i] = *(const float4*)&Ws[kq * 4 + i][tx * 4];
#pragma unroll
      for (int m = 0; m < 4; m++) {
        const float am[4] = {av[m].x, av[m].y, av[m].z, av[m].w};
#pragma unroll
        for (int i = 0; i < 4; i++) {
          acc[m][0] += am[i] * wv[i].x;
          acc[m][1] += am[i] * wv[i].y;
          acc[m][2] += am[i] * wv[i].z;
          acc[m][3] += am[i] * wv[i].w;
        }
      }
    }
  }
  const int col = tx * 4;
  const float4 bv = *(const float4*)&bias[col];
#pragma unroll
  for (int m = 0; m < 4; m++) {
    int n = n0 + ty * 4 + m;
    if (n < b) {
      h_store(&h[(size_t)n * HID + col + 0], fmaxf(acc[m][0] + bv.x, 0.f));
      h_store(&h[(size_t)n * HID + col + 1], fmaxf(acc[m][1] + bv.y, 0.f));
      h_store(&h[(size_t)n * HID + col + 2], fmaxf(acc[m][2] + bv.z, 0.f));
      h_store(&h[(size_t)n * HID + col + 3], fmaxf(acc[m][3] + bv.w, 0.f));
    }
  }
}

// ---- layer-2 tiled GEMM + fused pool: relu(b2 + [h1 | agg2/cnt] @ [root2; W2]) -> 64->2 -> graph sums ----
template <typename HT>
__global__ __launch_bounds__(256) void l2gemm_pool_k(
    const HT* __restrict__ h1, const float* __restrict__ agg, const float* __restrict__ cnt,
    const float* __restrict__ root, const float* __restrict__ W, const float* __restrict__ bias,
    const float* __restrict__ linW, const int* __restrict__ batch,
    float* __restrict__ gs, float* __restrict__ gc, int a, int b) {
  __shared__ float As[TILE][KC + 4];
  __shared__ float Ws[KC][TILE];
  const int t = threadIdx.x;
  const int tx = t & 15, ty = t >> 4;
  const int n0 = a + blockIdx.x * TILE;
  float acc[4][4] = {};

  for (int kc = 0; kc < 256 / KC; kc++) {
    __syncthreads();
#pragma unroll
    for (int p = 0; p < 4; p++) {
      int row = p * 16 + ty;
      int col = tx * 4;
      int n = n0 + row;
      if (n >= b) n = b - 1;
      int k = kc * KC + col;
      float4 v;
      if (kc == 0) {  // self segment from h1
        v.x = h_load(&h1[(size_t)n * HID + k + 0]);
        v.y = h_load(&h1[(size_t)n * HID + k + 1]);
        v.z = h_load(&h1[(size_t)n * HID + k + 2]);
        v.w = h_load(&h1[(size_t)n * HID + k + 3]);
      } else {
        int kk = k - HID;
        int r = kk >> 6;
        float sc = 1.0f / fmaxf(cnt[(size_t)n * NREL + r], 1.0f);
        float4 g = *(const float4*)&agg[(size_t)(n - a) * (NREL * HID) + kk];
        v.x = g.x * sc; v.y = g.y * sc; v.z = g.z * sc; v.w = g.w * sc;
      }
      *(float4*)&As[row][col] = v;
      int wk = kc * KC + row;
      float4 wv = (wk < HID) ? *(const float4*)&root[wk * HID + col]
                             : *(const float4*)&W[(wk - HID) * HID + col];
      *(float4*)&Ws[row][col] = wv;
    }
    __syncthreads();
#pragma unroll 4
    for (int kq = 0; kq < KC / 4; kq++) {
      float4 av[4], wv[4];
#pragma unroll
      for (int m = 0; m < 4; m++) av[m] = *(const float4*)&As[ty * 4 + m][kq * 4];
#pragma unroll
      for (int i = 0; i < 4; i++) wv[i] = *(const float4*)&Ws[kq * 4 + i][tx * 4];
#pragma unroll
      for (int m = 0; m < 4; m++) {
        const float am[4] = {av[m].x, av[m].y, av[m].z, av[m].w};
#pragma unroll
        for (int i = 0; i < 4; i++) {
          acc[m][0] += am[i] * wv[i].x;
          acc[m][1] += am[i] * wv[i].y;
          acc[m][2] += am[i] * wv[i].z;
          acc[m][3] += am[i] * wv[i].w;
        }
      }
    }
  }
  // fused epilogue: relu, project 64->2 over this thread's 4 cols, reduce across the
  // 16 lanes (tx) that share each row, atomic into per-graph sums.
  const int col = tx * 4;
  const float4 bv = *(const float4*)&bias[col];
  float lw0[4], lw1[4];
#pragma unroll
  for (int c = 0; c < 4; c++) {
    lw0[c] = linW[(col + c) * 2 + 0];
    lw1[c] = linW[(col + c) * 2 + 1];
  }
#pragma unroll
  for (int m = 0; m < 4; m++) {
    int n = n0 + ty * 4 + m;
    float v0 = fmaxf(acc[m][0] + bv.x, 0.f);
    float v1 = fmaxf(acc[m][1] + bv.y, 0.f);
    float v2 = fmaxf(acc[m][2] + bv.z, 0.f);
    float v3 = fmaxf(acc[m][3] + bv.w, 0.f);
    float t0 = v0 * lw0[0] + v1 * lw0[1] + v2 * lw0[2] + v3 * lw0[3];
    float t1 = v0 * lw1[0] + v1 * lw1[1] + v2 * lw1[2] + v3 * lw1[3];
#pragma unroll
    for (int o = 1; o < 16; o <<= 1) {
      t0 += __shfl_xor(t0, o, 16);
      t1 += __shfl_xor(t1, o, 16);
    }
    if (tx == 0 && n < b) {
      int g = batch[n];
      atomicAdd(&gs[g * 2 + 0], t0);
      atomicAdd(&gs[g * 2 + 1], t1);
      atomicAdd(&gc[g], 1.0f);
    }
  }
}

__global__ __launch_bounds__(256) void final_k(
    const float* __restrict__ gs, const float* __restrict__ gc,
    const float* __restrict__ linb, float* __restrict__ out, int G) {
  int i = blockIdx.x * 256 + threadIdx.x;
  if (i >= G * 2) return;
  int g = i >> 1, o = i & 1;
  out[i] = gs[i] / fmaxf(gc[g], 1.0f) + linb[o];
}

template <typename HT>
static void run_pipeline(const int* src, const int* dst, const int* et,
                         const int* sid, const int* cid, const int* pid,
                         const float* se, const float* ce, const float* pe,
                         const float* W1, const float* root1, const float* b1,
                         const float* W2, const float* root2, const float* b2,
                         const float* linW, const float* linb, const int* batch,
                         float* cnt, float* gs, float* gc, HT* h1, float* agg,
                         int N, int E, int G, int c1, int c2, float* out,
                         hipStream_t stream) {
  hipMemsetAsync(cnt, 0, (size_t)N * 3 * sizeof(float), stream);
  hipMemsetAsync(gs, 0, (size_t)G * 3 * sizeof(float), stream);

  for (int a = 0; a < N; a += c1) {
    int b = (a + c1 < N) ? (a + c1) : N;
    hipMemsetAsync(agg, 0, (size_t)(b - a) * (NREL * EMB) * sizeof(float), stream);
    l1edge_k<<<(unsigned)(((size_t)E * 32 + 255) / 256), 256, 0, stream>>>(
        src, dst, et, sid, cid, pid, se, ce, pe, agg, cnt, E, a, b);
    int blocks = (b - a + TILE - 1) / TILE;
    l1gemm_k<HT><<<blocks, 256, 0, stream>>>(agg, cnt, sid, cid, pid, se, ce, pe, root1, W1, b1,
                                             h1, a, b);
  }

  for (int a = 0; a < N; a += c2) {
    int b = (a + c2 < N) ? (a + c2) : N;
    hipMemsetAsync(agg, 0, (size_t)(b - a) * (NREL * HID) * sizeof(float), stream);
    l2edge_k<HT><<<(unsigned)(((size_t)E * 64 + 255) / 256), 256, 0, stream>>>(src, dst, et, h1,
                                                                               agg, E, a, b);
    int blocks = (b - a + TILE - 1) / TILE;
    l2gemm_pool_k<HT><<<blocks, 256, 0, stream>>>(h1, agg, cnt, root2, W2, b2, linW, batch, gs,
                                                  gc, a, b);
  }

  final_k<<<(G * 2 + 255) / 256, 256, 0, stream>>>(gs, gc, linb, out, G);
}

extern "C" void kernel_launch(void* const* d_in, const int* in_sizes, int n_in,
                              void* d_out, int out_size, void* d_ws, size_t ws_size,
                              hipStream_t stream) {
  const int* sid = (const int*)d_in[0];
  const int* cid = (const int*)d_in[1];
  const int* pid = (const int*)d_in[2];
  const int* ei = (const int*)d_in[3];
  const int* et = (const int*)d_in[4];
  const int* batch = (const int*)d_in[5];
  const float* se = (const float*)d_in[7];
  const float* ce = (const float*)d_in[8];
  const float* pe = (const float*)d_in[9];
  const float* W1 = (const float*)d_in[10];
  const float* root1 = (const float*)d_in[11];
  const float* b1 = (const float*)d_in[12];
  const float* W2 = (const float*)d_in[13];
  const float* root2 = (const float*)d_in[14];
  const float* b2 = (const float*)d_in[15];
  const float* linW = (const float*)d_in[16];
  const float* linb = (const float*)d_in[17];
  float* out = (float*)d_out;

  const int N = in_sizes[0];
  const int E = in_sizes[4];
  const int G = out_size / 2;
  const int* src = ei;
  const int* dst = ei + E;

  // ---- strict ws budget (floats). Layout: cnt[3N] | gs[2G] | gc[G] | h1 | agg ----
  size_t capf = ws_size / sizeof(float);
  const int MINCH = 1024;
  size_t head = (size_t)N * 3 + (size_t)G * 3;

  float* ws = (float*)d_ws;
  float* cnt = ws;
  float* gs = cnt + (size_t)N * 3;
  float* gc = gs + (size_t)G * 2;
  float* after_head = gc + (size_t)G;

  size_t fixed32 = head + (size_t)N * HID;
  size_t fixed16 = head + (size_t)N * HID / 2;

  if (capf >= fixed32 + (size_t)MINCH * (NREL * HID)) {
    float* h1 = after_head;
    float* agg = h1 + (size_t)N * HID;
    size_t varf = capf - fixed32;
    size_t c1s = varf / (NREL * EMB); if (c1s > (size_t)N) c1s = N;
    size_t c2s = varf / (NREL * HID); if (c2s > (size_t)N) c2s = N;
    int c1 = (int)(c1s & ~(size_t)63); if (c1 < 64) c1 = 64;
    int c2 = (int)(c2s & ~(size_t)63); if (c2 < 64) c2 = 64;
    run_pipeline<float>(src, dst, et, sid, cid, pid, se, ce, pe, W1, root1, b1, W2, root2, b2,
                        linW, linb, batch, cnt, gs, gc, h1, agg, N, E, G, c1, c2, out, stream);
  } else if (capf >= fixed16 + (size_t)MINCH * (NREL * HID)) {
    __hip_bfloat16* h1 = (__hip_bfloat16*)after_head;
    float* agg = after_head + (size_t)N * HID / 2;
    size_t varf = capf - fixed16;
    size_t c1s = varf / (NREL * EMB); if (c1s > (size_t)N) c1s = N;
    size_t c2s = varf / (NREL * HID); if (c2s > (size_t)N) c2s = N;
    int c1 = (int)(c1s & ~(size_t)63); if (c1 < 64) c1 = 64;
    int c2 = (int)(c2s & ~(size_t)63); if (c2 < 64) c2 = 64;
    run_pipeline<__hip_bfloat16>(src, dst, et, sid, cid, pid, se, ce, pe, W1, root1, b1, W2,
                                 root2, b2, linW, linb, batch, cnt, gs, gc, h1, agg, N, E, G, c1,
                                 c2, out, stream);
  }
  // else: ws too small for any correct plan — launch nothing (fails loudly, no OOB).
}

// Round 5
// 1224.109 us; speedup vs baseline: 1.8336x; 1.0607x over previous
//
#include <hip/hip_runtime.h>

#define NREL 3
#define EMB 32
#define HID 64
#define TILE 64

// ================= CSR build (sorted by (dst, rel)) =================
__global__ __launch_bounds__(256) void hist_k(const int* __restrict__ dst,
                                              const int* __restrict__ et,
                                              int* __restrict__ icnt, int E) {
  int e = blockIdx.x * 256 + threadIdx.x;
  if (e >= E) return;
  atomicAdd(&icnt[dst[e] * NREL + et[e]], 1);
}

// per-1024-item block sums
__global__ __launch_bounds__(256) void scan1_k(const int* __restrict__ icnt,
                                               int* __restrict__ psum, int M) {
  int base = blockIdx.x * 1024 + threadIdx.x * 4;
  int s = 0;
#pragma unroll
  for (int j = 0; j < 4; j++) {
    int i = base + j;
    if (i < M) s += icnt[i];
  }
  __shared__ int tmp[256];
  tmp[threadIdx.x] = s;
  __syncthreads();
  for (int off = 128; off > 0; off >>= 1) {
    if (threadIdx.x < off) tmp[threadIdx.x] += tmp[threadIdx.x + off];
    __syncthreads();
  }
  if (threadIdx.x == 0) psum[blockIdx.x] = tmp[0];
}

// single-block exclusive scan of psum[P]
__global__ __launch_bounds__(256) void scan2_k(int* __restrict__ psum, int P) {
  __shared__ int tmp[256];
  __shared__ int carry_s;
  if (threadIdx.x == 0) carry_s = 0;
  __syncthreads();
  for (int base = 0; base < P; base += 256) {
    int i = base + threadIdx.x;
    int v = (i < P) ? psum[i] : 0;
    tmp[threadIdx.x] = v;
    __syncthreads();
    for (int off = 1; off < 256; off <<= 1) {
      int u = (threadIdx.x >= off) ? tmp[threadIdx.x - off] : 0;
      __syncthreads();
      tmp[threadIdx.x] += u;
      __syncthreads();
    }
    int carry = carry_s;
    if (i < P) psum[i] = carry + tmp[threadIdx.x] - v;
    __syncthreads();
    if (threadIdx.x == 0) carry_s = carry + tmp[255];
    __syncthreads();
  }
}

// re-scan each 1024-block with its base -> exclusive offsets
__global__ __launch_bounds__(256) void scan3_k(const int* __restrict__ icnt,
                                               const int* __restrict__ psum,
                                               int* __restrict__ offs, int M) {
  int base = blockIdx.x * 1024 + threadIdx.x * 4;
  int v[4];
  int s = 0;
#pragma unroll
  for (int j = 0; j < 4; j++) {
    int i = base + j;
    v[j] = (i < M) ? icnt[i] : 0;
    s += v[j];
  }
  __shared__ int tmp[256];
  tmp[threadIdx.x] = s;
  __syncthreads();
  for (int off = 1; off < 256; off <<= 1) {
    int u = (threadIdx.x >= off) ? tmp[threadIdx.x - off] : 0;
    __syncthreads();
    tmp[threadIdx.x] += u;
    __syncthreads();
  }
  int run = psum[blockIdx.x] + tmp[threadIdx.x] - s;
#pragma unroll
  for (int j = 0; j < 4; j++) {
    int i = base + j;
    if (i < M) {
      offs[i] = run;
      run += v[j];
    }
  }
}

__global__ __launch_bounds__(256) void scatter_k(const int* __restrict__ src,
                                                 const int* __restrict__ dst,
                                                 const int* __restrict__ et,
                                                 int* __restrict__ cursor,
                                                 int* __restrict__ csr, int E) {
  int e = blockIdx.x * 256 + threadIdx.x;
  if (e >= E) return;
  int p = atomicAdd(&cursor[dst[e] * NREL + et[e]], 1);
  csr[p] = src[e];
}

// ====== layer-1 fused: CSR gather-agg (embeddings) + tiled GEMM -> h1 ======
// A = [x | mean_0 | mean_1 | mean_2]  (K=128), weights stacked [root1; W1].
__global__ __launch_bounds__(256) void l1fused_k(
    const int* __restrict__ sid, const int* __restrict__ cid, const int* __restrict__ pid,
    const float* __restrict__ se, const float* __restrict__ ce, const float* __restrict__ pe,
    const int* __restrict__ offs, const int* __restrict__ icnt, const int* __restrict__ csr,
    const float* __restrict__ root, const float* __restrict__ W, const float* __restrict__ bias,
    float* __restrict__ h1, int N) {
  __shared__ float As[TILE][132];  // 33.8 KB
  __shared__ float Ws[64][64];     // 16 KB
  const int t = threadIdx.x;
  const int tx = t & 15, ty = t >> 4;
  const int lane = t & 63, wave = t >> 6;
  const int n0 = blockIdx.x * TILE;
  const int col = lane & 31, half = lane >> 5;

  // ---- aggregation phase: each wave fills 16 rows of As ----
  for (int i = 0; i < 16; i++) {
    int row = wave * 16 + i;
    int n = n0 + row;
    if (n >= N) n = N - 1;
    float xv = se[sid[n] * EMB + col] + ce[cid[n] * EMB + col] + pe[pid[n] * EMB + col];
    float mm[NREL];
#pragma unroll
    for (int r = 0; r < NREL; r++) {
      int idx = n * NREL + r;
      int beg = offs[idx], len = icnt[idx];
      float acc = 0.f;
      for (int j = half; j < len; j += 2) {  // two halves walk alternating edges
        int s = csr[beg + j];
        acc += se[sid[s] * EMB + col] + ce[cid[s] * EMB + col] + pe[pid[s] * EMB + col];
      }
      acc += __shfl_xor(acc, 32, 64);
      mm[r] = acc / fmaxf((float)len, 1.f);
    }
    if (half == 0) {
      As[row][col] = xv;
      As[row][32 + col] = mm[0];
      As[row][64 + col] = mm[1];
      As[row][96 + col] = mm[2];
    }
  }
  __syncthreads();

  // ---- GEMM phase ----
  float acc[4][4] = {};
  for (int kc = 0; kc < 2; kc++) {
    if (kc) __syncthreads();
#pragma unroll
    for (int p = 0; p < 4; p++) {
      int row = p * 16 + ty;
      int c4 = tx * 4;
      int wk = kc * 64 + row;
      float4 wv = (wk < EMB) ? *(const float4*)&root[wk * HID + c4]
                             : *(const float4*)&W[(wk - EMB) * HID + c4];
      *(float4*)&Ws[row][c4] = wv;
    }
    __syncthreads();
#pragma unroll 4
    for (int kq = 0; kq < 16; kq++) {
      float4 av[4], wv[4];
#pragma unroll
      for (int m = 0; m < 4; m++) av[m] = *(const float4*)&As[ty * 4 + m][kc * 64 + kq * 4];
#pragma unroll
      for (int i = 0; i < 4; i++) wv[i] = *(const float4*)&Ws[kq * 4 + i][tx * 4];
#pragma unroll
      for (int m = 0; m < 4; m++) {
        const float am[4] = {av[m].x, av[m].y, av[m].z, av[m].w};
#pragma unroll
        for (int i = 0; i < 4; i++) {
          acc[m][0] += am[i] * wv[i].x;
          acc[m][1] += am[i] * wv[i].y;
          acc[m][2] += am[i] * wv[i].z;
          acc[m][3] += am[i] * wv[i].w;
        }
      }
    }
  }
  const int c4 = tx * 4;
  const float4 bv = *(const float4*)&bias[c4];
#pragma unroll
  for (int m = 0; m < 4; m++) {
    int n = n0 + ty * 4 + m;
    if (n < N) {
      float4 o;
      o.x = fmaxf(acc[m][0] + bv.x, 0.f);
      o.y = fmaxf(acc[m][1] + bv.y, 0.f);
      o.z = fmaxf(acc[m][2] + bv.z, 0.f);
      o.w = fmaxf(acc[m][3] + bv.w, 0.f);
      *(float4*)&h1[(size_t)n * HID + c4] = o;
    }
  }
}

// ====== layer-2 fused: CSR gather-agg (h1) per K-chunk + GEMM + pooled epilogue ======
__global__ __launch_bounds__(256) void l2fused_k(
    const float* __restrict__ h1,
    const int* __restrict__ offs, const int* __restrict__ icnt, const int* __restrict__ csr,
    const float* __restrict__ root, const float* __restrict__ W, const float* __restrict__ bias,
    const float* __restrict__ linW, const int* __restrict__ batch,
    float* __restrict__ gs, float* __restrict__ gc, int N) {
  __shared__ float As[TILE][68];  // 17.4 KB
  __shared__ float Ws[64][64];    // 16 KB
  const int t = threadIdx.x;
  const int tx = t & 15, ty = t >> 4;
  const int lane = t & 63, wave = t >> 6;
  const int n0 = blockIdx.x * TILE;
  float acc[4][4] = {};

  for (int kc = 0; kc < 4; kc++) {
    if (kc) __syncthreads();
    if (kc == 0) {  // self segment: copy h1 rows
#pragma unroll
      for (int p = 0; p < 4; p++) {
        int row = p * 16 + ty;
        int c4 = tx * 4;
        int n = n0 + row;
        if (n >= N) n = N - 1;
        *(float4*)&As[row][c4] = *(const float4*)&h1[(size_t)n * HID + c4];
      }
    } else {  // relation kc-1: walk CSR segment, gather h1[src] rows
      int r = kc - 1;
      for (int i = 0; i < 16; i++) {
        int row = wave * 16 + i;
        int n = n0 + row;
        if (n >= N) n = N - 1;
        int idx = n * NREL + r;
        int beg = offs[idx], len = icnt[idx];
        float a = 0.f;
        for (int j = 0; j < len; j++) a += h1[(size_t)csr[beg + j] * HID + lane];
        As[row][lane] = a / fmaxf((float)len, 1.f);
      }
    }
#pragma unroll
    for (int p = 0; p < 4; p++) {
      int row = p * 16 + ty;
      int c4 = tx * 4;
      int wk = kc * 64 + row;
      float4 wv = (wk < HID) ? *(const float4*)&root[wk * HID + c4]
                             : *(const float4*)&W[(wk - HID) * HID + c4];
      *(float4*)&Ws[row][c4] = wv;
    }
    __syncthreads();
#pragma unroll 4
    for (int kq = 0; kq < 16; kq++) {
      float4 av[4], wv[4];
#pragma unroll
      for (int m = 0; m < 4; m++) av[m] = *(const float4*)&As[ty * 4 + m][kq * 4];
#pragma unroll
      for (int i = 0; i < 4; i++) wv[i] = *(const float4*)&Ws[kq * 4 + i][tx * 4];
#pragma unroll
      for (int m = 0; m < 4; m++) {
        const float am[4] = {av[m].x, av[m].y, av[m].z, av[m].w};
#pragma unroll
        for (int i = 0; i < 4; i++) {
          acc[m][0] += am[i] * wv[i].x;
          acc[m][1] += am[i] * wv[i].y;
          acc[m][2] += am[i] * wv[i].z;
          acc[m][3] += am[i] * wv[i].w;
        }
      }
    }
  }
  // fused epilogue: bias+relu, project 64->2, reduce across 16 tx lanes, atomics
  const int c4 = tx * 4;
  const float4 bv = *(const float4*)&bias[c4];
  float lw0[4], lw1[4];
#pragma unroll
  for (int c = 0; c < 4; c++) {
    lw0[c] = linW[(c4 + c) * 2 + 0];
    lw1[c] = linW[(c4 + c) * 2 + 1];
  }
#pragma unroll
  for (int m = 0; m < 4; m++) {
    int n = n0 + ty * 4 + m;
    float v0 = fmaxf(acc[m][0] + bv.x, 0.f);
    float v1 = fmaxf(acc[m][1] + bv.y, 0.f);
    float v2 = fmaxf(acc[m][2] + bv.z, 0.f);
    float v3 = fmaxf(acc[m][3] + bv.w, 0.f);
    float t0 = v0 * lw0[0] + v1 * lw0[1] + v2 * lw0[2] + v3 * lw0[3];
    float t1 = v0 * lw1[0] + v1 * lw1[1] + v2 * lw1[2] + v3 * lw1[3];
#pragma unroll
    for (int o = 1; o < 16; o <<= 1) {
      t0 += __shfl_xor(t0, o, 16);
      t1 += __shfl_xor(t1, o, 16);
    }
    if (tx == 0 && n < N) {
      int g = batch[n];
      atomicAdd(&gs[g * 2 + 0], t0);
      atomicAdd(&gs[g * 2 + 1], t1);
      atomicAdd(&gc[g], 1.0f);
    }
  }
}

__global__ __launch_bounds__(256) void final_k(const float* __restrict__ gs,
                                               const float* __restrict__ gc,
                                               const float* __restrict__ linb,
                                               float* __restrict__ out, int G) {
  int i = blockIdx.x * 256 + threadIdx.x;
  if (i >= G * 2) return;
  int g = i >> 1, o = i & 1;
  out[i] = gs[i] / fmaxf(gc[g], 1.0f) + linb[o];
}

extern "C" void kernel_launch(void* const* d_in, const int* in_sizes, int n_in,
                              void* d_out, int out_size, void* d_ws, size_t ws_size,
                              hipStream_t stream) {
  const int* sid = (const int*)d_in[0];
  const int* cid = (const int*)d_in[1];
  const int* pid = (const int*)d_in[2];
  const int* ei = (const int*)d_in[3];
  const int* et = (const int*)d_in[4];
  const int* batch = (const int*)d_in[5];
  const float* se = (const float*)d_in[7];
  const float* ce = (const float*)d_in[8];
  const float* pe = (const float*)d_in[9];
  const float* W1 = (const float*)d_in[10];
  const float* root1 = (const float*)d_in[11];
  const float* b1 = (const float*)d_in[12];
  const float* W2 = (const float*)d_in[13];
  const float* root2 = (const float*)d_in[14];
  const float* b2 = (const float*)d_in[15];
  const float* linW = (const float*)d_in[16];
  const float* linb = (const float*)d_in[17];
  float* out = (float*)d_out;

  const int N = in_sizes[0];
  const int E = in_sizes[4];
  const int G = out_size / 2;
  const int* src = ei;
  const int* dst = ei + E;
  const int M = N * NREL;
  const int P = (M + 1023) / 1024;

  // ---- workspace layout (strictly budgeted) ----
  char* w = (char*)d_ws;
  float* h1 = (float*)w;      w += (size_t)N * HID * sizeof(float);
  float* gs = (float*)w;      w += (size_t)G * 2 * sizeof(float);
  float* gc = (float*)w;      w += (size_t)G * sizeof(float);
  int* icnt = (int*)w;        w += (size_t)M * sizeof(int);
  int* offs = (int*)w;        w += (size_t)M * sizeof(int);
  int* cursor = (int*)w;      w += (size_t)M * sizeof(int);
  int* csr = (int*)w;         w += (size_t)E * sizeof(int);
  int* psum = (int*)w;        w += (size_t)P * sizeof(int);
  if ((size_t)(w - (char*)d_ws) > ws_size) return;  // ws too small: fail loudly, no OOB

  hipMemsetAsync(icnt, 0, (size_t)M * sizeof(int), stream);
  hipMemsetAsync(gs, 0, (size_t)G * 3 * sizeof(float), stream);

  hist_k<<<(E + 255) / 256, 256, 0, stream>>>(dst, et, icnt, E);
  scan1_k<<<P, 256, 0, stream>>>(icnt, psum, M);
  scan2_k<<<1, 256, 0, stream>>>(psum, P);
  scan3_k<<<P, 256, 0, stream>>>(icnt, psum, offs, M);
  hipMemcpyAsync(cursor, offs, (size_t)M * sizeof(int), hipMemcpyDeviceToDevice, stream);
  scatter_k<<<(E + 255) / 256, 256, 0, stream>>>(src, dst, et, cursor, csr, E);

  int blocks = (N + TILE - 1) / TILE;
  l1fused_k<<<blocks, 256, 0, stream>>>(sid, cid, pid, se, ce, pe, offs, icnt, csr, root1, W1,
                                        b1, h1, N);
  l2fused_k<<<blocks, 256, 0, stream>>>(h1, offs, icnt, csr, root2, W2, b2, linW, batch, gs, gc,
                                        N);
  final_k<<<(G * 2 + 255) / 256, 256, 0, stream>>>(gs, gc, linb, out, G);
}